// Round 10
// baseline (4451.699 us; speedup 1.0000x reference)
//
#include <hip/hip_runtime.h>

namespace {

constexpr int kT  = 256;
constexpr int kRS = 140;   // activation row stride; phys(k)=k+4*(k>>5) -> max 139

typedef float f2 __attribute__((ext_vector_type(2)));
typedef float f4 __attribute__((ext_vector_type(4)));

__device__ __forceinline__ float fast_tanh(float x) {
    float e = __expf(2.0f * x);
    return 1.0f - 2.0f * __builtin_amdgcn_rcpf(e + 1.0f);
}

__device__ __forceinline__ float dpp_xor1(float x) {
    return __builtin_bit_cast(float, __builtin_amdgcn_update_dpp(
        0, __builtin_bit_cast(int, x), 0xB1, 0xF, 0xF, true)); // quad [1,0,3,2]
}
__device__ __forceinline__ float dpp_xor2(float x) {
    return __builtin_bit_cast(float, __builtin_amdgcn_update_dpp(
        0, __builtin_bit_cast(int, x), 0x4E, 0xF, 0xF, true)); // quad [2,3,0,1]
}
template <int PAT>
__device__ __forceinline__ float swz(float x) {
    return __builtin_bit_cast(float,
        __builtin_amdgcn_ds_swizzle(__builtin_bit_cast(int, x), PAT));
}

// bank-spread: chunk c=k>>5 starts at bank 4c; all accesses <=2-way (free)
__device__ __forceinline__ int phys(int k) { return k + 4 * (k >> 5); }

// 512 threads, min 2 waves/EU: R6 showed this shape compiles ~116 VGPR, no
// spill -> fits 4 waves/SIMD. Grid = 512 blocks (2 rows each) so 2 blocks/CU
// actually reside: 16 waves/CU + two independent barrier groups.
__global__ __launch_bounds__(512, 2)
void hybrid_ode_kernel(
    const float* __restrict__ y0,
    const float* __restrict__ t_span,
    const float* __restrict__ meal,
    const float* __restrict__ tvns,
    const float* __restrict__ W_in, const float* __restrict__ b_in,
    const float* __restrict__ W_h,  const float* __restrict__ b_h,
    const float* __restrict__ W_out,const float* __restrict__ b_out,
    float* __restrict__ out)
{
    const int tid = threadIdx.x;
    const int w   = tid >> 6;            // wave 0..7
    const int l   = tid & 63;
    const int kc  = l & 15;              // k-chunk: k = 8kc..8kc+7
    const int g   = (w << 2) | (l >> 4); // 0..31: j-group (4 cols)
    const int jb  = g * 4;
    const int out8 = kc & 7;             // output owned after reduce-scatter
    const int r_p  = out8 & 1;
    const int j_p  = jb + (out8 >> 1);
    const bool wr_own = (kc & 8) == 0;
    const bool pb0 = (kc & 1) != 0;
    const bool pb1 = (kc & 2) != 0;
    const bool pb2 = (kc & 4) != 0;
    const int row = blockIdx.x * 2 + (w & 1);  // dereferenced only when w<2

    __shared__ __align__(16) float hp0[2 * kRS];
    __shared__ __align__(16) float hp1[2 * kRS];
    __shared__ float win_s[9 * 128];
    __shared__ float bi_s[128];
    __shared__ float wo_s[128 * 6];
    __shared__ float bo_s[8];
    __shared__ float bh_s[3 * 128];
    __shared__ float xb[2][12];          // [t, yc0..5, yc3, v]

    // ---- stage small weights to LDS (covered by first dyn barrier)
    for (int idx = tid; idx < 1152; idx += 512) win_s[idx] = W_in[idx];
    for (int idx = tid; idx < 768;  idx += 512) wo_s[idx]  = W_out[idx];
    if (tid < 384) bh_s[tid] = b_h[tid];
    if (tid < 128) bi_s[tid] = b_in[tid];
    if (tid < 6)   bo_s[tid] = b_out[tid];

    // ---- hidden weights: full residency, 96 VGPRs/thread
    f2 wgt[3][4][4];   // [layer][k-pair p][jj]: k = 8kc+2p (+1), col jb+jj
    #pragma unroll
    for (int ll = 0; ll < 3; ++ll)
        #pragma unroll
        for (int p = 0; p < 4; ++p)
            #pragma unroll
            for (int jj = 0; jj < 4; ++jj) {
                const float* s = W_h + (size_t)(ll * 128 + 8 * kc + 2 * p) * 128 + jb + jj;
                f2 v; v.x = s[0]; v.y = s[128];
                wgt[ll][p][jj] = v;
            }

    // ---- RK4 state on waves 0..1 (lane-uniform; wave w carries row)
    float y[6] = {0,0,0,0,0,0};
    if (w < 2) {
        #pragma unroll
        for (int s = 0; s < 6; ++s) y[s] = y0[row * 6 + s];
        if (l == 0) {
            #pragma unroll
            for (int s = 0; s < 6; ++s) out[(size_t)row * kT * 6 + s] = y[s];
        }
    }
    const float* mrow = meal + (size_t)row * kT;
    const float* vrow = tvns + (size_t)row * kT;

    auto wxb = [&](float t, const float* yc, float v) {
        if (w < 2 && l == 0) {
            xb[w][0] = t;
            #pragma unroll
            for (int s = 0; s < 6; ++s) xb[w][1 + s] = yc[s];
            xb[w][7] = yc[3];
            xb[w][8] = v;
        }
    };

    // one dyn eval: 5 barriers; p[] valid on waves 0..1 (includes b_out)
    auto dyn = [&](float* p) {
        __syncthreads();                          // xb (and staging) ready

        // input layer 9->128, waves 0..3: wave w -> row w>>1, 64 cols
        if (w < 4) {
            const int r = w >> 1;
            const int c = ((w & 1) << 6) | l;
            float s = bi_s[c];
            #pragma unroll
            for (int k = 0; k < 9; ++k) s += xb[r][k] * win_s[k * 128 + c];
            hp0[r * kRS + phys(c)] = fast_tanh(s);
        }
        __syncthreads();

        // 3 hidden layers 128->128, ping-pong
        #pragma unroll
        for (int ll = 0; ll < 3; ++ll) {
            const float* rb = (ll & 1) ? hp1 : hp0;
            float*       wb = (ll & 1) ? hp0 : hp1;

            const int o0 = 8 * kc + 4 * (kc >> 2);   // = phys(8*kc)
            f4 q00 = *(const f4*)(rb + o0);
            f4 q01 = *(const f4*)(rb + o0 + 4);
            f4 q10 = *(const f4*)(rb + kRS + o0);
            f4 q11 = *(const f4*)(rb + kRS + o0 + 4);
            f2 h0[4], h1[4];
            h0[0] = __builtin_shufflevector(q00, q00, 0, 1);
            h0[1] = __builtin_shufflevector(q00, q00, 2, 3);
            h0[2] = __builtin_shufflevector(q01, q01, 0, 1);
            h0[3] = __builtin_shufflevector(q01, q01, 2, 3);
            h1[0] = __builtin_shufflevector(q10, q10, 0, 1);
            h1[1] = __builtin_shufflevector(q10, q10, 2, 3);
            h1[2] = __builtin_shufflevector(q11, q11, 0, 1);
            h1[3] = __builtin_shufflevector(q11, q11, 2, 3);

            f2 acc[4][2];
            #pragma unroll
            for (int p2 = 0; p2 < 4; ++p2)
                #pragma unroll
                for (int jj = 0; jj < 4; ++jj) {
                    const f2 wv = wgt[ll][p2][jj];
                    if (p2 == 0) {
                        acc[jj][0] = h0[0] * wv;
                        acc[jj][1] = h1[0] * wv;
                    } else {
                        acc[jj][0] = h0[p2] * wv + acc[jj][0];
                        acc[jj][1] = h1[p2] * wv + acc[jj][1];
                    }
                }

            float A[8];   // A[(jj<<1)|r]
            #pragma unroll
            for (int jj = 0; jj < 4; ++jj) {
                A[(jj << 1) | 0] = acc[jj][0].x + acc[jj][0].y;
                A[(jj << 1) | 1] = acc[jj][1].x + acc[jj][1].y;
            }

            // reduce-scatter over the 16 kc-lanes: lane ends with out = kc&7
            float B[4];
            #pragma unroll
            for (int i2 = 0; i2 < 4; ++i2) {
                float keep = pb0 ? A[2*i2+1] : A[2*i2];
                float give = pb0 ? A[2*i2]   : A[2*i2+1];
                B[i2] = keep + dpp_xor1(give);
            }
            float C[2];
            #pragma unroll
            for (int i2 = 0; i2 < 2; ++i2) {
                float keep = pb1 ? B[2*i2+1] : B[2*i2];
                float give = pb1 ? B[2*i2]   : B[2*i2+1];
                C[i2] = keep + dpp_xor2(give);
            }
            float D;
            {
                float keep = pb2 ? C[1] : C[0];
                float give = pb2 ? C[0] : C[1];
                D = keep + swz<0x101F>(give);       // xor4
            }
            float S = D + swz<0x201F>(D);           // xor8: merge halves
            if (wr_own)
                wb[r_p * kRS + phys(j_p)] = fast_tanh(S + bh_s[ll * 128 + j_p]);
            __syncthreads();
        }

        // output layer 128->6: waves 0..1 (one per row); h lives in hp1
        if (w < 2) {
            float hA = hp1[w * kRS + phys(l)];
            float hB = hp1[w * kRS + phys(l + 64)];
            #pragma unroll
            for (int s = 0; s < 6; ++s) {
                float ps = hA * wo_s[l * 6 + s] + hB * wo_s[(l + 64) * 6 + s];
                ps += dpp_xor1(ps);
                ps += dpp_xor2(ps);
                ps += swz<0x101F>(ps);
                ps += swz<0x201F>(ps);
                ps += swz<0x401F>(ps);
                ps += __shfl_xor(ps, 32);
                p[s] = ps + bo_s[s];
            }
        }
    };

    // ODE core: reads yc of THIS eval back from xb (shortens live ranges)
    auto ode = [&](float m, const float* p, float* d) {
        const float G = xb[w][1], I = xb[w][2], N = xb[w][3];
        const float L = xb[w][4], GE = xb[w][5], F = xb[w][6];
        d[0] = -0.01f*I*G + 0.05f*GE                                    + p[0];
        d[1] = (G/(100.0f+G))*(1.0f + 2.0f*L/(5.0f+L)) - 0.1f*I         + p[1];
        d[2] = -0.05f*N                                                 + p[2];
        d[3] = 0.05f*GE - 0.2f*L                                        + p[3];
        d[4] = m - 0.05f*GE                                             + p[4];
        d[5] = -0.01f*I*F                                               + p[5];
    };

    for (int i = 0; i < kT - 1; ++i) {
        float t0 = 0, t1 = 0, dt = 0, tm = 0;
        float m0 = 0, m1 = 0, mm = 0, v0 = 0, v1 = 0, vm = 0;
        if (w < 2) {
            t0 = t_span[i]; t1 = t_span[i + 1]; dt = t1 - t0; tm = t0 + 0.5f * dt;
            m0 = mrow[i]; m1 = mrow[i + 1]; mm = 0.5f * (m0 + m1);
            v0 = vrow[i]; v1 = vrow[i + 1]; vm = 0.5f * (v0 + v1);
        }
        float d[6], ksum[6], yc[6], p[6];

        wxb(t0, y, v0);
        dyn(p);
        if (w < 2) {
            ode(m0, p, d);
            #pragma unroll
            for (int s = 0; s < 6; ++s) { ksum[s] = d[s]; yc[s] = y[s] + 0.5f * dt * d[s]; }
        }
        wxb(tm, yc, vm);
        dyn(p);
        if (w < 2) {
            ode(mm, p, d);
            #pragma unroll
            for (int s = 0; s < 6; ++s) { ksum[s] += 2.0f * d[s]; yc[s] = y[s] + 0.5f * dt * d[s]; }
        }
        wxb(tm, yc, vm);
        dyn(p);
        if (w < 2) {
            ode(mm, p, d);
            #pragma unroll
            for (int s = 0; s < 6; ++s) { ksum[s] += 2.0f * d[s]; yc[s] = y[s] + dt * d[s]; }
        }
        wxb(t1, yc, v1);
        dyn(p);
        if (w < 2) {
            ode(m1, p, d);
            #pragma unroll
            for (int s = 0; s < 6; ++s) y[s] += (dt * (1.0f / 6.0f)) * (ksum[s] + d[s]);
            if (l == 0) {
                #pragma unroll
                for (int s = 0; s < 6; ++s)
                    out[((size_t)row * kT + (i + 1)) * 6 + s] = y[s];
            }
        }
    }
}

} // namespace

extern "C" void kernel_launch(void* const* d_in, const int* in_sizes, int n_in,
                              void* d_out, int out_size, void* d_ws, size_t ws_size,
                              hipStream_t stream) {
    const float* y0     = (const float*)d_in[0];
    const float* t_span = (const float*)d_in[1];
    const float* meal   = (const float*)d_in[2];
    const float* tvns   = (const float*)d_in[3];
    const float* W_in   = (const float*)d_in[4];
    const float* b_in   = (const float*)d_in[5];
    const float* W_h    = (const float*)d_in[6];
    const float* b_h    = (const float*)d_in[7];
    const float* W_out  = (const float*)d_in[8];
    const float* b_out  = (const float*)d_in[9];
    float* out          = (float*)d_out;

    hipLaunchKernelGGL(hybrid_ode_kernel, dim3(512), dim3(512), 0, stream,
                       y0, t_span, meal, tvns,
                       W_in, b_in, W_h, b_h, W_out, b_out, out);
}

// Round 11
// 4445.113 us; speedup vs baseline: 1.0015x; 1.0015x over previous
//
#include <hip/hip_runtime.h>

namespace {

constexpr int kT  = 256;
constexpr int kRS = 140;   // activation row stride; phys(k)=k+4*(k>>5) -> max 139

typedef float f2 __attribute__((ext_vector_type(2)));
typedef float f4 __attribute__((ext_vector_type(4)));

__device__ __forceinline__ float fast_tanh(float x) {
    float e = __expf(2.0f * x);
    return 1.0f - 2.0f * __builtin_amdgcn_rcpf(e + 1.0f);
}

__device__ __forceinline__ float dpp_xor1(float x) {
    return __builtin_bit_cast(float, __builtin_amdgcn_update_dpp(
        0, __builtin_bit_cast(int, x), 0xB1, 0xF, 0xF, true)); // quad [1,0,3,2]
}
__device__ __forceinline__ float dpp_xor2(float x) {
    return __builtin_bit_cast(float, __builtin_amdgcn_update_dpp(
        0, __builtin_bit_cast(int, x), 0x4E, 0xF, 0xF, true)); // quad [2,3,0,1]
}
template <int PAT>
__device__ __forceinline__ float swz(float x) {
    return __builtin_bit_cast(float,
        __builtin_amdgcn_ds_swizzle(__builtin_bit_cast(int, x), PAT));
}

// bank-spread: chunk c=k>>5 starts at bank 4c
__device__ __forceinline__ int phys(int k) { return k + 4 * (k >> 5); }

// 512-thread blocks compile spill-free (R6/R10: 96-116 VGPR, WRITE=6144).
// LDS padded to ~60 KB: backend occupancy target = 2 blocks/CU (16 waves,
// 4/SIMD, 128-reg budget) and HW can co-schedule exactly 2 (120<=160 KB).
constexpr int kPad = 12288;   // floats: 48 KB

__global__ __launch_bounds__(512, 2)
void hybrid_ode_kernel(
    const float* __restrict__ y0,
    const float* __restrict__ t_span,
    const float* __restrict__ meal,
    const float* __restrict__ tvns,
    const float* __restrict__ W_in, const float* __restrict__ b_in,
    const float* __restrict__ W_h,  const float* __restrict__ b_h,
    const float* __restrict__ W_out,const float* __restrict__ b_out,
    float* __restrict__ out)
{
    const int tid = threadIdx.x;
    const int w   = tid >> 6;            // wave 0..7
    const int l   = tid & 63;
    const int kc  = l & 15;              // k-chunk: k = 8kc..8kc+7
    const int g   = (w << 2) | (l >> 4); // 0..31: j-group (4 cols)
    const int jb  = g * 4;
    const int out8 = kc & 7;             // output owned after reduce-scatter
    const int r_p  = out8 & 1;
    const int j_p  = jb + (out8 >> 1);
    const bool wr_own = (kc & 8) == 0;
    const bool pb0 = (kc & 1) != 0;
    const bool pb1 = (kc & 2) != 0;
    const bool pb2 = (kc & 4) != 0;
    const int row = blockIdx.x * 2 + (w & 1);  // dereferenced only when w<2

    __shared__ __align__(16) float hp0[2 * kRS];
    __shared__ __align__(16) float hp1[2 * kRS];
    __shared__ float win_s[9 * 128];
    __shared__ float bi_s[128];
    __shared__ float wo_s[128 * 6];
    __shared__ float bo_s[8];
    __shared__ float bh_s[3 * 128];
    __shared__ float xb[2][12];          // [t, yc0..5, yc3, v]
    __shared__ float pad_s[kPad];        // occupancy hammer (never touched)

    // keep pad_s alive: uniform impossible condition (inputs are finite
    // random data; t_span[0]=0). Same work every call.
    const float guard = t_span[0];
    if (guard == -12345678.0f) {
        pad_s[tid] = guard;
        out[(size_t)tid] = pad_s[tid ^ 1];
    }

    // ---- stage small weights to LDS (covered by first dyn barrier)
    for (int idx = tid; idx < 1152; idx += 512) win_s[idx] = W_in[idx];
    for (int idx = tid; idx < 768;  idx += 512) wo_s[idx]  = W_out[idx];
    if (tid < 384) bh_s[tid] = b_h[tid];
    if (tid < 128) bi_s[tid] = b_in[tid];
    if (tid < 6)   bo_s[tid] = b_out[tid];

    // ---- hidden weights: full residency, 96 VGPRs/thread
    f2 wgt[3][4][4];   // [layer][k-pair p][jj]: k = 8kc+2p (+1), col jb+jj
    #pragma unroll
    for (int ll = 0; ll < 3; ++ll)
        #pragma unroll
        for (int p = 0; p < 4; ++p)
            #pragma unroll
            for (int jj = 0; jj < 4; ++jj) {
                const float* s = W_h + (size_t)(ll * 128 + 8 * kc + 2 * p) * 128 + jb + jj;
                f2 v; v.x = s[0]; v.y = s[128];
                wgt[ll][p][jj] = v;
            }

    // ---- RK4 state on waves 0..1 (lane-uniform; wave w carries row)
    float y[6] = {0,0,0,0,0,0};
    if (w < 2) {
        #pragma unroll
        for (int s = 0; s < 6; ++s) y[s] = y0[row * 6 + s];
        if (l == 0) {
            #pragma unroll
            for (int s = 0; s < 6; ++s) out[(size_t)row * kT * 6 + s] = y[s];
        }
    }
    const float* mrow = meal + (size_t)row * kT;
    const float* vrow = tvns + (size_t)row * kT;

    auto wxb = [&](float t, const float* yc, float v) {
        if (w < 2 && l == 0) {
            xb[w][0] = t;
            #pragma unroll
            for (int s = 0; s < 6; ++s) xb[w][1 + s] = yc[s];
            xb[w][7] = yc[3];
            xb[w][8] = v;
        }
    };

    // one dyn eval: 5 barriers; p[] valid on waves 0..1 (includes b_out)
    auto dyn = [&](float* p) {
        __syncthreads();                          // xb (and staging) ready

        // input layer 9->128, waves 0..3: wave w -> row w>>1, 64 cols
        if (w < 4) {
            const int r = w >> 1;
            const int c = ((w & 1) << 6) | l;
            float s = bi_s[c];
            #pragma unroll
            for (int k = 0; k < 9; ++k) s += xb[r][k] * win_s[k * 128 + c];
            hp0[r * kRS + phys(c)] = fast_tanh(s);
        }
        __syncthreads();

        // 3 hidden layers 128->128, ping-pong
        #pragma unroll
        for (int ll = 0; ll < 3; ++ll) {
            const float* rb = (ll & 1) ? hp1 : hp0;
            float*       wb = (ll & 1) ? hp0 : hp1;

            const int o0 = 8 * kc + 4 * (kc >> 2);   // = phys(8*kc)
            f4 q00 = *(const f4*)(rb + o0);
            f4 q01 = *(const f4*)(rb + o0 + 4);
            f4 q10 = *(const f4*)(rb + kRS + o0);
            f4 q11 = *(const f4*)(rb + kRS + o0 + 4);
            f2 h0[4], h1[4];
            h0[0] = __builtin_shufflevector(q00, q00, 0, 1);
            h0[1] = __builtin_shufflevector(q00, q00, 2, 3);
            h0[2] = __builtin_shufflevector(q01, q01, 0, 1);
            h0[3] = __builtin_shufflevector(q01, q01, 2, 3);
            h1[0] = __builtin_shufflevector(q10, q10, 0, 1);
            h1[1] = __builtin_shufflevector(q10, q10, 2, 3);
            h1[2] = __builtin_shufflevector(q11, q11, 0, 1);
            h1[3] = __builtin_shufflevector(q11, q11, 2, 3);

            f2 acc[4][2];
            #pragma unroll
            for (int p2 = 0; p2 < 4; ++p2)
                #pragma unroll
                for (int jj = 0; jj < 4; ++jj) {
                    const f2 wv = wgt[ll][p2][jj];
                    if (p2 == 0) {
                        acc[jj][0] = h0[0] * wv;
                        acc[jj][1] = h1[0] * wv;
                    } else {
                        acc[jj][0] = h0[p2] * wv + acc[jj][0];
                        acc[jj][1] = h1[p2] * wv + acc[jj][1];
                    }
                }

            float A[8];   // A[(jj<<1)|r]
            #pragma unroll
            for (int jj = 0; jj < 4; ++jj) {
                A[(jj << 1) | 0] = acc[jj][0].x + acc[jj][0].y;
                A[(jj << 1) | 1] = acc[jj][1].x + acc[jj][1].y;
            }

            // reduce-scatter over the 16 kc-lanes: lane ends with out = kc&7
            float B[4];
            #pragma unroll
            for (int i2 = 0; i2 < 4; ++i2) {
                float keep = pb0 ? A[2*i2+1] : A[2*i2];
                float give = pb0 ? A[2*i2]   : A[2*i2+1];
                B[i2] = keep + dpp_xor1(give);
            }
            float C[2];
            #pragma unroll
            for (int i2 = 0; i2 < 2; ++i2) {
                float keep = pb1 ? B[2*i2+1] : B[2*i2];
                float give = pb1 ? B[2*i2]   : B[2*i2+1];
                C[i2] = keep + dpp_xor2(give);
            }
            float D;
            {
                float keep = pb2 ? C[1] : C[0];
                float give = pb2 ? C[0] : C[1];
                D = keep + swz<0x101F>(give);       // xor4
            }
            float S = D + swz<0x201F>(D);           // xor8: merge halves
            if (wr_own)
                wb[r_p * kRS + phys(j_p)] = fast_tanh(S + bh_s[ll * 128 + j_p]);
            __syncthreads();
        }

        // output layer 128->6: waves 0..1 (one per row); h lives in hp1
        if (w < 2) {
            float hA = hp1[w * kRS + phys(l)];
            float hB = hp1[w * kRS + phys(l + 64)];
            #pragma unroll
            for (int s = 0; s < 6; ++s) {
                float ps = hA * wo_s[l * 6 + s] + hB * wo_s[(l + 64) * 6 + s];
                ps += dpp_xor1(ps);
                ps += dpp_xor2(ps);
                ps += swz<0x101F>(ps);
                ps += swz<0x201F>(ps);
                ps += swz<0x401F>(ps);
                ps += __shfl_xor(ps, 32);
                p[s] = ps + bo_s[s];
            }
        }
    };

    // ODE core: reads yc of THIS eval back from xb (shortens live ranges)
    auto ode = [&](float m, const float* p, float* d) {
        const float G = xb[w][1], I = xb[w][2], N = xb[w][3];
        const float L = xb[w][4], GE = xb[w][5], F = xb[w][6];
        d[0] = -0.01f*I*G + 0.05f*GE                                    + p[0];
        d[1] = (G/(100.0f+G))*(1.0f + 2.0f*L/(5.0f+L)) - 0.1f*I         + p[1];
        d[2] = -0.05f*N                                                 + p[2];
        d[3] = 0.05f*GE - 0.2f*L                                        + p[3];
        d[4] = m - 0.05f*GE                                             + p[4];
        d[5] = -0.01f*I*F                                               + p[5];
    };

    for (int i = 0; i < kT - 1; ++i) {
        float t0 = 0, t1 = 0, dt = 0, tm = 0;
        float m0 = 0, m1 = 0, mm = 0, v0 = 0, v1 = 0, vm = 0;
        if (w < 2) {
            t0 = t_span[i]; t1 = t_span[i + 1]; dt = t1 - t0; tm = t0 + 0.5f * dt;
            m0 = mrow[i]; m1 = mrow[i + 1]; mm = 0.5f * (m0 + m1);
            v0 = vrow[i]; v1 = vrow[i + 1]; vm = 0.5f * (v0 + v1);
        }
        float d[6], ksum[6], yc[6], p[6];

        wxb(t0, y, v0);
        dyn(p);
        if (w < 2) {
            ode(m0, p, d);
            #pragma unroll
            for (int s = 0; s < 6; ++s) { ksum[s] = d[s]; yc[s] = y[s] + 0.5f * dt * d[s]; }
        }
        wxb(tm, yc, vm);
        dyn(p);
        if (w < 2) {
            ode(mm, p, d);
            #pragma unroll
            for (int s = 0; s < 6; ++s) { ksum[s] += 2.0f * d[s]; yc[s] = y[s] + 0.5f * dt * d[s]; }
        }
        wxb(tm, yc, vm);
        dyn(p);
        if (w < 2) {
            ode(mm, p, d);
            #pragma unroll
            for (int s = 0; s < 6; ++s) { ksum[s] += 2.0f * d[s]; yc[s] = y[s] + dt * d[s]; }
        }
        wxb(t1, yc, v1);
        dyn(p);
        if (w < 2) {
            ode(m1, p, d);
            #pragma unroll
            for (int s = 0; s < 6; ++s) y[s] += (dt * (1.0f / 6.0f)) * (ksum[s] + d[s]);
            if (l == 0) {
                #pragma unroll
                for (int s = 0; s < 6; ++s)
                    out[((size_t)row * kT + (i + 1)) * 6 + s] = y[s];
            }
        }
    }
}

} // namespace

extern "C" void kernel_launch(void* const* d_in, const int* in_sizes, int n_in,
                              void* d_out, int out_size, void* d_ws, size_t ws_size,
                              hipStream_t stream) {
    const float* y0     = (const float*)d_in[0];
    const float* t_span = (const float*)d_in[1];
    const float* meal   = (const float*)d_in[2];
    const float* tvns   = (const float*)d_in[3];
    const float* W_in   = (const float*)d_in[4];
    const float* b_in   = (const float*)d_in[5];
    const float* W_h    = (const float*)d_in[6];
    const float* b_h    = (const float*)d_in[7];
    const float* W_out  = (const float*)d_in[8];
    const float* b_out  = (const float*)d_in[9];
    float* out          = (float*)d_out;

    hipLaunchKernelGGL(hybrid_ode_kernel, dim3(512), dim3(512), 0, stream,
                       y0, t_span, meal, tvns,
                       W_in, b_in, W_h, b_h, W_out, b_out, out);
}